// Round 12
// baseline (127.054 us; speedup 1.0000x reference)
//
#include <hip/hip_runtime.h>
#include <cstdint>
#include <cstddef>

#define B_ 256
#define IN_ 100000
#define H_ 512
#define OUT_ 30000
#define OUTP_ 30080
#define S_ 256
#define NSTEPS 3125   // IN_/32
#define KSPLIT 128

typedef __attribute__((ext_vector_type(4))) float f32x4;
typedef __attribute__((ext_vector_type(2))) float f32x2;
typedef __attribute__((ext_vector_type(4))) int i32x4;
typedef __attribute__((ext_vector_type(8))) short short8;
typedef __attribute__((ext_vector_type(8))) unsigned short ushort8;
typedef __attribute__((ext_vector_type(4))) unsigned short ushort4_;
typedef __attribute__((ext_vector_type(2))) uint32_t uint32x2;
typedef __attribute__((ext_vector_type(4))) uint32_t uint32x4;

static __device__ __forceinline__ uint32_t cvtpk(float lo, float hi) {
  uint32_t r;
  asm("v_cvt_pk_bf16_f32 %0, %1, %2" : "=v"(r) : "v"(lo), "v"(hi));
  return r;
}
static __device__ __forceinline__ unsigned short f2bf(float f) {
  union { float f; uint32_t u; } c; c.f = f;
  uint32_t u = c.u;
  u += 0x7FFFu + ((u >> 16) & 1u);   // RNE
  return (unsigned short)(u >> 16);
}
static __device__ __forceinline__ float bf2f(unsigned short h) {
  union { uint32_t u; float f; } c; c.u = ((uint32_t)h) << 16;
  return c.f;
}
// 16B fp32 -> 8B bf16 store
static __device__ __forceinline__ void pack4_store(unsigned short* dst, f32x4 a) {
  uint32x2 v;
  v[0] = cvtpk(a[0], a[1]); v[1] = cvtpk(a[2], a[3]);
  *(uint32x2*)dst = v;
}

// Raw barrier: only drain LDS ops; in-flight global loads survive.
#define BARRIER() { asm volatile("s_waitcnt lgkmcnt(0)" ::: "memory"); \
    __builtin_amdgcn_s_barrier(); \
    __builtin_amdgcn_sched_barrier(0); }

// ---------------------------------------------------------------------------
// GEMM1 split-K — r11 structure (256x256 tile, KSPLIT=128, grid 256, nt w1).
// ROUND-12 DELTA: `part` stores are ALSO non-temporal. Mechanism (confirmed
// r10, w1 nt: 120.4->102.3us): zero-reuse traffic through L2 burns the
// ~1-line/cy/XCD fill budget. part is consumed by the NEXT kernel from
// other XCDs — caching it in this XCD's L2 is pure waste.
// ---------------------------------------------------------------------------
__global__ __launch_bounds__(512, 2) void k_gemm1(const float* __restrict__ x,
                                                  const float* __restrict__ w1,
                                                  unsigned short* __restrict__ part) {
  __shared__ alignas(16) unsigned short Ab[2][B_ * 32];    // 16 KB each
  __shared__ alignas(16) unsigned short Bb[2][256 * 32];   // 16 KB each
  const int tid = threadIdx.x;
  const int d = blockIdx.x;
  const int xcd = d & 7;
  const int i = d >> 3;
  const int kc = xcd + ((i >> 1) << 3);   // 0..127
  const int nblk = i & 1;                  // 0..1
  const int s0 = (kc * NSTEPS) / KSPLIT;
  const int s1 = ((kc + 1) * NSTEPS) / KSPLIT;
  const int U = s1 - s0;   // 24 or 25 for all kc

  // A staging: 8 threads/row, lane-contiguous 16B; rows arow+{0,64,128,192}
  const int arow = tid >> 3;                    // 0..63
  const int asl = tid & 7;                      // 16B slot in 128B row-step
  const size_t rowStride64 = (size_t)64 * IN_;
  const float* gA = x + (size_t)arow * IN_ + (size_t)s0 * 32 + asl * 4;
  const int afz = (arow >> 1) & 3;              // swizzle (row+64j invariant)
  const int aslSw = ((asl >> 1) ^ afz) * 8 + (asl & 1) * 4;  // ushort offset in row

  // B staging: 8 threads/row, lane-contiguous 16B; rows br+{0,64,128,192} of 256
  const int br = tid >> 3;                      // 0..63
  const int bj = tid & 7;
  const float* gB = w1 + (size_t)(nblk * 256 + br) * IN_ + (size_t)s0 * 32 + bj * 4;
  const int bOff = br * 32 + (((bj >> 1) ^ ((br >> 1) & 3)) * 8) + (bj & 1) * 4;

  const int lane = tid & 63;
  const int wid = tid >> 6;
  const int wrow = wid >> 1;                    // 0..3  (64-row stripe)
  const int wcol = wid & 1;                     // 0..1  (128-col stripe)
  const int fr = lane & 15;
  const int fq = lane >> 4;                     // 0..3 (16B k-slot)
  const int Ra = wrow * 64 + fr;
  const int Rb = wcol * 128 + fr;
  const int aBase = Ra * 32 + (fq ^ ((Ra >> 1) & 3)) * 8;
  const int bBase = Rb * 32 + (fq ^ ((Rb >> 1) & 3)) * 8;

  f32x4 zero = {0.f, 0.f, 0.f, 0.f};
  f32x4 acc[4][8];
  #pragma unroll
  for (int mf = 0; mf < 4; ++mf)
    #pragma unroll
    for (int nf = 0; nf < 8; ++nf) acc[mf][nf] = zero;

  f32x4 P0, P1, P2, P3, P4, P5, P6, P7;
  f32x4 Q0, Q1, Q2, Q3, Q4, Q5, Q6, Q7;

#define G1_ISSUE(S, u) if ((u) < U) { \
    const float* pa_ = gA + (size_t)(u) * 32; \
    S##0 = *(const f32x4*)pa_; \
    S##1 = *(const f32x4*)(pa_ + rowStride64); \
    S##2 = *(const f32x4*)(pa_ + 2 * rowStride64); \
    S##3 = *(const f32x4*)(pa_ + 3 * rowStride64); \
    const float* pb_ = gB + (size_t)(u) * 32; \
    S##4 = __builtin_nontemporal_load((const f32x4*)pb_); \
    S##5 = __builtin_nontemporal_load((const f32x4*)(pb_ + rowStride64)); \
    S##6 = __builtin_nontemporal_load((const f32x4*)(pb_ + 2 * rowStride64)); \
    S##7 = __builtin_nontemporal_load((const f32x4*)(pb_ + 3 * rowStride64)); }

#define G1_PACK(S, b) { \
    pack4_store(&Ab[b][(arow)       * 32 + aslSw], S##0); \
    pack4_store(&Ab[b][(arow + 64)  * 32 + aslSw], S##1); \
    pack4_store(&Ab[b][(arow + 128) * 32 + aslSw], S##2); \
    pack4_store(&Ab[b][(arow + 192) * 32 + aslSw], S##3); \
    pack4_store(&Bb[b][bOff], S##4); \
    pack4_store(&Bb[b][bOff +  64 * 32], S##5); \
    pack4_store(&Bb[b][bOff + 128 * 32], S##6); \
    pack4_store(&Bb[b][bOff + 192 * 32], S##7); }

#define COMPUTE_TILE(b) { \
    short8 af_[4], bf_[8]; \
    _Pragma("unroll") for (int mf_ = 0; mf_ < 4; ++mf_) af_[mf_] = *(const short8*)&Ab[b][aBase + mf_ * 512]; \
    _Pragma("unroll") for (int nf_ = 0; nf_ < 8; ++nf_) bf_[nf_] = *(const short8*)&Bb[b][bBase + nf_ * 512]; \
    __builtin_amdgcn_s_setprio(1); \
    _Pragma("unroll") for (int mf_ = 0; mf_ < 4; ++mf_) \
      _Pragma("unroll") for (int nf_ = 0; nf_ < 8; ++nf_) \
        acc[mf_][nf_] = __builtin_amdgcn_mfma_f32_16x16x32_bf16(af_[mf_], bf_[nf_], acc[mf_][nf_], 0, 0, 0); \
    __builtin_amdgcn_s_setprio(0); }

  // prologue: 2 steps in flight, step 0 staged
  G1_ISSUE(P, 0)
  G1_ISSUE(Q, 1)
  G1_PACK(P, 0)
  BARRIER()

  int u = 0;
  #pragma unroll 1
  while (u + 1 < U) {
    G1_ISSUE(P, u + 2)
    COMPUTE_TILE(0)               // step u
    G1_PACK(Q, 1)                 // step u+1
    BARRIER()
    G1_ISSUE(Q, u + 3)
    COMPUTE_TILE(1)               // step u+1
    if (u + 2 < U) { G1_PACK(P, 0) }
    BARRIER()
    u += 2;
  }
  if (u < U) COMPUTE_TILE(0)      // U odd (25): last step

  unsigned short* pp = part + (size_t)kc * (B_ * H_);
  #pragma unroll
  for (int mf = 0; mf < 4; ++mf) {
    #pragma unroll
    for (int nf = 0; nf < 8; ++nf) {
      const int row0 = wrow * 64 + mf * 16 + fq * 4;
      const int col = nblk * 256 + wcol * 128 + nf * 16 + fr;
      #pragma unroll
      for (int j = 0; j < 4; ++j)
        __builtin_nontemporal_store(f2bf(acc[mf][nf][j]),
                                    &pp[(size_t)(row0 + j) * H_ + col]);
    }
  }
}

// ---------------------------------------------------------------------------
// h_bf16[m][n] = bf16(relu(b1[n] + sum_kc partial))
// ROUND-12: part loads nt (33.6 MB, zero reuse, written by other XCDs).
// ---------------------------------------------------------------------------
__global__ void k_reduce_h(const unsigned short* __restrict__ part,
                           const float* __restrict__ b1,
                           unsigned short* __restrict__ hbf) {
  int t = blockIdx.x * 256 + threadIdx.x;        // 0..32767
  int base = t * 4;
  int n = base & (H_ - 1);
  float a0 = b1[n], a1 = b1[n + 1], a2 = b1[n + 2], a3 = b1[n + 3];
  #pragma unroll 8
  for (int kc = 0; kc < KSPLIT; ++kc) {
    ushort4_ v = __builtin_nontemporal_load(
        (const ushort4_*)(part + (size_t)kc * (B_ * H_) + base));
    a0 += bf2f(v[0]); a1 += bf2f(v[1]); a2 += bf2f(v[2]); a3 += bf2f(v[3]);
  }
  ushort4_ o;
  o[0] = f2bf(fmaxf(a0, 0.f));
  o[1] = f2bf(fmaxf(a1, 0.f));
  o[2] = f2bf(fmaxf(a2, 0.f));
  o[3] = f2bf(fmaxf(a3, 0.f));
  *(ushort4_*)(hbf + base) = o;
}

// ---------------------------------------------------------------------------
// GEMM2 (256 x 128-col tile x K=512), direct codebook gather, fused column
// log_softmax. ROUND-12: codes loads nt (31 MB, one block per row);
// out stores nt (123 MB, zero reuse — write-allocate fills were burning the
// L2 fill budget per the r10-confirmed mechanism). hbf/cb stay cached (hot).
// ---------------------------------------------------------------------------
__global__ __launch_bounds__(512, 2) void k_gemm2(const unsigned short* __restrict__ hbf,
                                                  const int* __restrict__ codes,
                                                  const float* __restrict__ cb,
                                                  const float* __restrict__ b2,
                                                  float* __restrict__ out) {
  __shared__ alignas(16) unsigned short Ab[2][B_ * 32];
  __shared__ alignas(16) unsigned short Bb[2][128 * 32];
  __shared__ float sred[4][128];
  const int tid = threadIdx.x;
  const int n0 = blockIdx.x * 128;

  // A staging: 4 threads/row, lane-contiguous 16B; rows arow2+{0,128}
  const int arow2 = tid >> 2;                   // 0..127
  const int asl2 = tid & 3;                     // 16B slot in 64B row-step
  const unsigned short* gA = hbf + (size_t)arow2 * H_ + asl2 * 8;
  const int afz2 = (arow2 >> 1) & 3;            // (row+128) invariant
  const int aslSw2 = (asl2 ^ afz2) * 8;
  const int aOffA = arow2 * 32 + aslSw2;
  const int aOffB = (arow2 + 128) * 32 + aslSw2;

  // B staging: thread -> row rb (4 threads/row), slot-quad s4 (4 codebook slots)
  const int rb = tid >> 2;
  const int s4 = tid & 3;
  const int rbo = (n0 + rb < OUT_) ? (n0 + rb) : (OUT_ - 1);
  const int* gC = codes + (size_t)rbo * S_ + s4 * 4;
  const int bOff = rb * 32 + (s4 ^ ((rb >> 1) & 3)) * 8;

  const int lane = tid & 63;
  const int wid = tid >> 6;
  const int wrow = wid >> 1;
  const int wcol = wid & 1;
  const int fr = lane & 15;
  const int fq = lane >> 4;
  const int Ra = wrow * 64 + fr;
  const int Rb = wcol * 64 + fr;
  const int aBase = Ra * 32 + (fq ^ ((Ra >> 1) & 3)) * 8;
  const int bBase = Rb * 32 + (fq ^ ((Rb >> 1) & 3)) * 8;

  f32x4 zero = {0.f, 0.f, 0.f, 0.f};
  f32x4 acc[4][4];
  #pragma unroll
  for (int mf = 0; mf < 4; ++mf)
    #pragma unroll
    for (int nf = 0; nf < 4; ++nf) acc[mf][nf] = zero;

  ushort8 Pa0, Pa1, Qa0, Qa1;
  i32x4 Pc, Qc;
  f32x2 Pg0, Pg1, Pg2, Pg3, Qg0, Qg1, Qg2, Qg3;

#define G2_IC(S, u) if ((u) < 16) { \
    S##a0 = *(const ushort8*)(gA + (size_t)(u) * 32); \
    S##a1 = *(const ushort8*)(gA + (size_t)(u) * 32 + (size_t)128 * H_); \
    S##c  = __builtin_nontemporal_load((const i32x4*)(gC + (u) * 16)); }

#define G2_IG(S, u) if ((u) < 16) { \
    const int slb_ = (u) * 16 + s4 * 4; \
    S##g0 = *(const f32x2*)(cb + ((size_t)(slb_ + 0) * 256 + (S##c[0] & 255)) * 2); \
    S##g1 = *(const f32x2*)(cb + ((size_t)(slb_ + 1) * 256 + (S##c[1] & 255)) * 2); \
    S##g2 = *(const f32x2*)(cb + ((size_t)(slb_ + 2) * 256 + (S##c[2] & 255)) * 2); \
    S##g3 = *(const f32x2*)(cb + ((size_t)(slb_ + 3) * 256 + (S##c[3] & 255)) * 2); }

#define G2_PACK(S, BUF) { \
    *(ushort8*)&Ab[BUF][aOffA] = S##a0; \
    *(ushort8*)&Ab[BUF][aOffB] = S##a1; \
    uint32x4 bw_; \
    bw_[0] = cvtpk(S##g0[0], S##g0[1]); bw_[1] = cvtpk(S##g1[0], S##g1[1]); \
    bw_[2] = cvtpk(S##g2[0], S##g2[1]); bw_[3] = cvtpk(S##g3[0], S##g3[1]); \
    *(uint32x4*)&Bb[BUF][bOff] = bw_; }

#define G2_COMPUTE(BUF) { \
    short8 af_[4], bf_[4]; \
    _Pragma("unroll") for (int mf_ = 0; mf_ < 4; ++mf_) af_[mf_] = *(const short8*)&Ab[BUF][aBase + mf_ * 512]; \
    _Pragma("unroll") for (int nf_ = 0; nf_ < 4; ++nf_) bf_[nf_] = *(const short8*)&Bb[BUF][bBase + nf_ * 512]; \
    __builtin_amdgcn_s_setprio(1); \
    _Pragma("unroll") for (int mf_ = 0; mf_ < 4; ++mf_) \
      _Pragma("unroll") for (int nf_ = 0; nf_ < 4; ++nf_) \
        acc[mf_][nf_] = __builtin_amdgcn_mfma_f32_16x16x32_bf16(af_[mf_], bf_[nf_], acc[mf_][nf_], 0, 0, 0); \
    __builtin_amdgcn_s_setprio(0); }

  G2_IC(P, 0)
  G2_IC(Q, 1)
  G2_IG(P, 0)
  G2_PACK(P, 0)
  BARRIER()

  #pragma unroll 1
  for (int u = 0; u < 16; u += 2) {
    G2_IC(P, u + 2)
    G2_IG(Q, u + 1)
    G2_COMPUTE(0)
    G2_PACK(Q, 1)
    BARRIER()
    G2_IC(Q, u + 3)
    G2_IG(P, u + 2)
    G2_COMPUTE(1)
    if (u + 2 < 16) { G2_PACK(P, 0) }
    BARRIER()
  }

  // ---- epilogue: + b2, then column-wise log_softmax over the 256 rows ----
  float b2v[4];
  #pragma unroll
  for (int nf = 0; nf < 4; ++nf) {
    int col = n0 + wcol * 64 + nf * 16 + fr;
    b2v[nf] = (col < OUT_) ? b2[col] : 0.f;
  }
  #pragma unroll
  for (int mf = 0; mf < 4; ++mf)
    #pragma unroll
    for (int nf = 0; nf < 4; ++nf)
      #pragma unroll
      for (int j = 0; j < 4; ++j) acc[mf][nf][j] += b2v[nf];

  float cmax[4];
  #pragma unroll
  for (int nf = 0; nf < 4; ++nf) {
    float m = -3.4e38f;
    #pragma unroll
    for (int mf = 0; mf < 4; ++mf)
      #pragma unroll
      for (int j = 0; j < 4; ++j) m = fmaxf(m, acc[mf][nf][j]);
    m = fmaxf(m, __shfl_xor(m, 16, 64));
    m = fmaxf(m, __shfl_xor(m, 32, 64));
    cmax[nf] = m;
  }
  if (lane < 16) {
    #pragma unroll
    for (int nf = 0; nf < 4; ++nf) sred[wrow][wcol * 64 + nf * 16 + lane] = cmax[nf];
  }
  __syncthreads();
  float cm[4];
  #pragma unroll
  for (int nf = 0; nf < 4; ++nf) {
    int ci = wcol * 64 + nf * 16 + fr;
    cm[nf] = fmaxf(fmaxf(sred[0][ci], sred[1][ci]), fmaxf(sred[2][ci], sred[3][ci]));
  }
  __syncthreads();

  float cs[4];
  #pragma unroll
  for (int nf = 0; nf < 4; ++nf) {
    float sum = 0.f;
    #pragma unroll
    for (int mf = 0; mf < 4; ++mf)
      #pragma unroll
      for (int j = 0; j < 4; ++j) sum += expf(acc[mf][nf][j] - cm[nf]);
    sum += __shfl_xor(sum, 16, 64);
    sum += __shfl_xor(sum, 32, 64);
    cs[nf] = sum;
  }
  if (lane < 16) {
    #pragma unroll
    for (int nf = 0; nf < 4; ++nf) sred[wrow][wcol * 64 + nf * 16 + lane] = cs[nf];
  }
  __syncthreads();
  float lden[4];
  #pragma unroll
  for (int nf = 0; nf < 4; ++nf) {
    int ci = wcol * 64 + nf * 16 + fr;
    lden[nf] = logf(sred[0][ci] + sred[1][ci] + sred[2][ci] + sred[3][ci]);
  }

  #pragma unroll
  for (int mf = 0; mf < 4; ++mf) {
    #pragma unroll
    for (int nf = 0; nf < 4; ++nf) {
      int col = n0 + wcol * 64 + nf * 16 + fr;
      if (col < OUT_) {
        int row0 = wrow * 64 + mf * 16 + fq * 4;
        #pragma unroll
        for (int j = 0; j < 4; ++j)
          __builtin_nontemporal_store(acc[mf][nf][j] - cm[nf] - lden[nf],
                                      &out[(size_t)(row0 + j) * OUT_ + col]);
      }
    }
  }
}

// ---------------------------------------------------------------------------
extern "C" void kernel_launch(void* const* d_in, const int* in_sizes, int n_in,
                              void* d_out, int out_size, void* d_ws, size_t ws_size,
                              hipStream_t stream) {
  const float* x      = (const float*)d_in[0];
  const float* w1     = (const float*)d_in[1];
  const float* b1     = (const float*)d_in[2];
  const float* cb     = (const float*)d_in[3];
  const int*   codes  = (const int*)d_in[4];
  const float* b2     = (const float*)d_in[5];
  float* out = (float*)d_out;

  char* ws = (char*)d_ws;
  unsigned short* part = (unsigned short*)ws;                          // 33.6 MB
  unsigned short* hbf  = (unsigned short*)(ws + (size_t)KSPLIT * B_ * H_ * 2);

  hipLaunchKernelGGL(k_gemm1,    dim3(2 * KSPLIT),          dim3(512), 0, stream, x, w1, part);
  hipLaunchKernelGGL(k_reduce_h, dim3((B_ * H_ / 4) / 256), dim3(256), 0, stream, part, b1, hbf);
  hipLaunchKernelGGL(k_gemm2,    dim3(OUTP_ / 128),         dim3(512), 0, stream, hbf, codes, cb, b2, out);
}

// Round 13
// 104.065 us; speedup vs baseline: 1.2209x; 1.2209x over previous
//
#include <hip/hip_runtime.h>
#include <cstdint>
#include <cstddef>

#define B_ 256
#define IN_ 100000
#define H_ 512
#define OUT_ 30000
#define OUTP_ 30080
#define S_ 256
#define NSTEPS 3125   // IN_/32
#define KSPLIT 128

typedef __attribute__((ext_vector_type(4))) float f32x4;
typedef __attribute__((ext_vector_type(2))) float f32x2;
typedef __attribute__((ext_vector_type(4))) int i32x4;
typedef __attribute__((ext_vector_type(8))) short short8;
typedef __attribute__((ext_vector_type(8))) unsigned short ushort8;
typedef __attribute__((ext_vector_type(4))) unsigned short ushort4_;
typedef __attribute__((ext_vector_type(2))) uint32_t uint32x2;
typedef __attribute__((ext_vector_type(4))) uint32_t uint32x4;

static __device__ __forceinline__ uint32_t cvtpk(float lo, float hi) {
  uint32_t r;
  asm("v_cvt_pk_bf16_f32 %0, %1, %2" : "=v"(r) : "v"(lo), "v"(hi));
  return r;
}
static __device__ __forceinline__ unsigned short f2bf(float f) {
  union { float f; uint32_t u; } c; c.f = f;
  uint32_t u = c.u;
  u += 0x7FFFu + ((u >> 16) & 1u);   // RNE
  return (unsigned short)(u >> 16);
}
static __device__ __forceinline__ float bf2f(unsigned short h) {
  union { uint32_t u; float f; } c; c.u = ((uint32_t)h) << 16;
  return c.f;
}
// 16B fp32 -> 8B bf16 store
static __device__ __forceinline__ void pack4_store(unsigned short* dst, f32x4 a) {
  uint32x2 v;
  v[0] = cvtpk(a[0], a[1]); v[1] = cvtpk(a[2], a[3]);
  *(uint32x2*)dst = v;
}

// Raw barrier: only drain LDS ops; in-flight global loads survive.
#define BARRIER() { asm volatile("s_waitcnt lgkmcnt(0)" ::: "memory"); \
    __builtin_amdgcn_s_barrier(); \
    __builtin_amdgcn_sched_barrier(0); }

// ---------------------------------------------------------------------------
// GEMM1 split-K — r11 structure EXACTLY (256x256 tile, KSPLIT=128, grid 256,
// nt w1 loads, CACHED part stores). ROUND-13: r12's regression (101.8->127.1)
// is attributed to the nt STORES — nt bypasses L2 write-combining, so the
// 8B/4B-per-lane part/out stores hit DRAM as partial lines (read-modify-
// write). Stores reverted to cached; nt kept/added on zero-reuse READ
// streams only (w1 here; part-read + codes in the kernels below), which
// share the r10-confirmed fill-budget mechanism.
// ---------------------------------------------------------------------------
__global__ __launch_bounds__(512, 2) void k_gemm1(const float* __restrict__ x,
                                                  const float* __restrict__ w1,
                                                  unsigned short* __restrict__ part) {
  __shared__ alignas(16) unsigned short Ab[2][B_ * 32];    // 16 KB each
  __shared__ alignas(16) unsigned short Bb[2][256 * 32];   // 16 KB each
  const int tid = threadIdx.x;
  const int d = blockIdx.x;
  const int xcd = d & 7;
  const int i = d >> 3;
  const int kc = xcd + ((i >> 1) << 3);   // 0..127
  const int nblk = i & 1;                  // 0..1
  const int s0 = (kc * NSTEPS) / KSPLIT;
  const int s1 = ((kc + 1) * NSTEPS) / KSPLIT;
  const int U = s1 - s0;   // 24 or 25 for all kc

  // A staging: 8 threads/row, lane-contiguous 16B; rows arow+{0,64,128,192}
  const int arow = tid >> 3;                    // 0..63
  const int asl = tid & 7;                      // 16B slot in 128B row-step
  const size_t rowStride64 = (size_t)64 * IN_;
  const float* gA = x + (size_t)arow * IN_ + (size_t)s0 * 32 + asl * 4;
  const int afz = (arow >> 1) & 3;              // swizzle (row+64j invariant)
  const int aslSw = ((asl >> 1) ^ afz) * 8 + (asl & 1) * 4;  // ushort offset in row

  // B staging: 8 threads/row, lane-contiguous 16B; rows br+{0,64,128,192} of 256
  const int br = tid >> 3;                      // 0..63
  const int bj = tid & 7;
  const float* gB = w1 + (size_t)(nblk * 256 + br) * IN_ + (size_t)s0 * 32 + bj * 4;
  const int bOff = br * 32 + (((bj >> 1) ^ ((br >> 1) & 3)) * 8) + (bj & 1) * 4;

  const int lane = tid & 63;
  const int wid = tid >> 6;
  const int wrow = wid >> 1;                    // 0..3  (64-row stripe)
  const int wcol = wid & 1;                     // 0..1  (128-col stripe)
  const int fr = lane & 15;
  const int fq = lane >> 4;                     // 0..3 (16B k-slot)
  const int Ra = wrow * 64 + fr;
  const int Rb = wcol * 128 + fr;
  const int aBase = Ra * 32 + (fq ^ ((Ra >> 1) & 3)) * 8;
  const int bBase = Rb * 32 + (fq ^ ((Rb >> 1) & 3)) * 8;

  f32x4 zero = {0.f, 0.f, 0.f, 0.f};
  f32x4 acc[4][8];
  #pragma unroll
  for (int mf = 0; mf < 4; ++mf)
    #pragma unroll
    for (int nf = 0; nf < 8; ++nf) acc[mf][nf] = zero;

  f32x4 P0, P1, P2, P3, P4, P5, P6, P7;
  f32x4 Q0, Q1, Q2, Q3, Q4, Q5, Q6, Q7;

#define G1_ISSUE(S, u) if ((u) < U) { \
    const float* pa_ = gA + (size_t)(u) * 32; \
    S##0 = *(const f32x4*)pa_; \
    S##1 = *(const f32x4*)(pa_ + rowStride64); \
    S##2 = *(const f32x4*)(pa_ + 2 * rowStride64); \
    S##3 = *(const f32x4*)(pa_ + 3 * rowStride64); \
    const float* pb_ = gB + (size_t)(u) * 32; \
    S##4 = __builtin_nontemporal_load((const f32x4*)pb_); \
    S##5 = __builtin_nontemporal_load((const f32x4*)(pb_ + rowStride64)); \
    S##6 = __builtin_nontemporal_load((const f32x4*)(pb_ + 2 * rowStride64)); \
    S##7 = __builtin_nontemporal_load((const f32x4*)(pb_ + 3 * rowStride64)); }

#define G1_PACK(S, b) { \
    pack4_store(&Ab[b][(arow)       * 32 + aslSw], S##0); \
    pack4_store(&Ab[b][(arow + 64)  * 32 + aslSw], S##1); \
    pack4_store(&Ab[b][(arow + 128) * 32 + aslSw], S##2); \
    pack4_store(&Ab[b][(arow + 192) * 32 + aslSw], S##3); \
    pack4_store(&Bb[b][bOff], S##4); \
    pack4_store(&Bb[b][bOff +  64 * 32], S##5); \
    pack4_store(&Bb[b][bOff + 128 * 32], S##6); \
    pack4_store(&Bb[b][bOff + 192 * 32], S##7); }

#define COMPUTE_TILE(b) { \
    short8 af_[4], bf_[8]; \
    _Pragma("unroll") for (int mf_ = 0; mf_ < 4; ++mf_) af_[mf_] = *(const short8*)&Ab[b][aBase + mf_ * 512]; \
    _Pragma("unroll") for (int nf_ = 0; nf_ < 8; ++nf_) bf_[nf_] = *(const short8*)&Bb[b][bBase + nf_ * 512]; \
    __builtin_amdgcn_s_setprio(1); \
    _Pragma("unroll") for (int mf_ = 0; mf_ < 4; ++mf_) \
      _Pragma("unroll") for (int nf_ = 0; nf_ < 8; ++nf_) \
        acc[mf_][nf_] = __builtin_amdgcn_mfma_f32_16x16x32_bf16(af_[mf_], bf_[nf_], acc[mf_][nf_], 0, 0, 0); \
    __builtin_amdgcn_s_setprio(0); }

  // prologue: 2 steps in flight, step 0 staged
  G1_ISSUE(P, 0)
  G1_ISSUE(Q, 1)
  G1_PACK(P, 0)
  BARRIER()

  int u = 0;
  #pragma unroll 1
  while (u + 1 < U) {
    G1_ISSUE(P, u + 2)
    COMPUTE_TILE(0)               // step u
    G1_PACK(Q, 1)                 // step u+1
    BARRIER()
    G1_ISSUE(Q, u + 3)
    COMPUTE_TILE(1)               // step u+1
    if (u + 2 < U) { G1_PACK(P, 0) }
    BARRIER()
    u += 2;
  }
  if (u < U) COMPUTE_TILE(0)      // U odd (25): last step

  unsigned short* pp = part + (size_t)kc * (B_ * H_);
  #pragma unroll
  for (int mf = 0; mf < 4; ++mf) {
    #pragma unroll
    for (int nf = 0; nf < 8; ++nf) {
      const int row0 = wrow * 64 + mf * 16 + fq * 4;
      const int col = nblk * 256 + wcol * 128 + nf * 16 + fr;
      #pragma unroll
      for (int j = 0; j < 4; ++j)
        pp[(size_t)(row0 + j) * H_ + col] = f2bf(acc[mf][nf][j]);
    }
  }
}

// ---------------------------------------------------------------------------
// h_bf16[m][n] = bf16(relu(b1[n] + sum_kc partial))
// ROUND-13: part loads nt (33.6 MB zero-reuse READ stream — r10 mechanism);
// hbf store stays cached (r12 lesson: nt stores lose write-combining).
// ---------------------------------------------------------------------------
__global__ void k_reduce_h(const unsigned short* __restrict__ part,
                           const float* __restrict__ b1,
                           unsigned short* __restrict__ hbf) {
  int t = blockIdx.x * 256 + threadIdx.x;        // 0..32767
  int base = t * 4;
  int n = base & (H_ - 1);
  float a0 = b1[n], a1 = b1[n + 1], a2 = b1[n + 2], a3 = b1[n + 3];
  #pragma unroll 8
  for (int kc = 0; kc < KSPLIT; ++kc) {
    ushort4_ v = __builtin_nontemporal_load(
        (const ushort4_*)(part + (size_t)kc * (B_ * H_) + base));
    a0 += bf2f(v[0]); a1 += bf2f(v[1]); a2 += bf2f(v[2]); a3 += bf2f(v[3]);
  }
  ushort4_ o;
  o[0] = f2bf(fmaxf(a0, 0.f));
  o[1] = f2bf(fmaxf(a1, 0.f));
  o[2] = f2bf(fmaxf(a2, 0.f));
  o[3] = f2bf(fmaxf(a3, 0.f));
  *(ushort4_*)(hbf + base) = o;
}

// ---------------------------------------------------------------------------
// GEMM2 (256 x 128-col tile x K=512), direct codebook gather, fused column
// log_softmax. ROUND-13: codes loads nt (31 MB, one block per row — read
// stream, r10 mechanism); out stores CACHED (r12 lesson). hbf/cb hot.
// ---------------------------------------------------------------------------
__global__ __launch_bounds__(512, 2) void k_gemm2(const unsigned short* __restrict__ hbf,
                                                  const int* __restrict__ codes,
                                                  const float* __restrict__ cb,
                                                  const float* __restrict__ b2,
                                                  float* __restrict__ out) {
  __shared__ alignas(16) unsigned short Ab[2][B_ * 32];
  __shared__ alignas(16) unsigned short Bb[2][128 * 32];
  __shared__ float sred[4][128];
  const int tid = threadIdx.x;
  const int n0 = blockIdx.x * 128;

  // A staging: 4 threads/row, lane-contiguous 16B; rows arow2+{0,128}
  const int arow2 = tid >> 2;                   // 0..127
  const int asl2 = tid & 3;                     // 16B slot in 64B row-step
  const unsigned short* gA = hbf + (size_t)arow2 * H_ + asl2 * 8;
  const int afz2 = (arow2 >> 1) & 3;            // (row+128) invariant
  const int aslSw2 = (asl2 ^ afz2) * 8;
  const int aOffA = arow2 * 32 + aslSw2;
  const int aOffB = (arow2 + 128) * 32 + aslSw2;

  // B staging: thread -> row rb (4 threads/row), slot-quad s4 (4 codebook slots)
  const int rb = tid >> 2;
  const int s4 = tid & 3;
  const int rbo = (n0 + rb < OUT_) ? (n0 + rb) : (OUT_ - 1);
  const int* gC = codes + (size_t)rbo * S_ + s4 * 4;
  const int bOff = rb * 32 + (s4 ^ ((rb >> 1) & 3)) * 8;

  const int lane = tid & 63;
  const int wid = tid >> 6;
  const int wrow = wid >> 1;
  const int wcol = wid & 1;
  const int fr = lane & 15;
  const int fq = lane >> 4;
  const int Ra = wrow * 64 + fr;
  const int Rb = wcol * 64 + fr;
  const int aBase = Ra * 32 + (fq ^ ((Ra >> 1) & 3)) * 8;
  const int bBase = Rb * 32 + (fq ^ ((Rb >> 1) & 3)) * 8;

  f32x4 zero = {0.f, 0.f, 0.f, 0.f};
  f32x4 acc[4][4];
  #pragma unroll
  for (int mf = 0; mf < 4; ++mf)
    #pragma unroll
    for (int nf = 0; nf < 4; ++nf) acc[mf][nf] = zero;

  ushort8 Pa0, Pa1, Qa0, Qa1;
  i32x4 Pc, Qc;
  f32x2 Pg0, Pg1, Pg2, Pg3, Qg0, Qg1, Qg2, Qg3;

#define G2_IC(S, u) if ((u) < 16) { \
    S##a0 = *(const ushort8*)(gA + (size_t)(u) * 32); \
    S##a1 = *(const ushort8*)(gA + (size_t)(u) * 32 + (size_t)128 * H_); \
    S##c  = __builtin_nontemporal_load((const i32x4*)(gC + (u) * 16)); }

#define G2_IG(S, u) if ((u) < 16) { \
    const int slb_ = (u) * 16 + s4 * 4; \
    S##g0 = *(const f32x2*)(cb + ((size_t)(slb_ + 0) * 256 + (S##c[0] & 255)) * 2); \
    S##g1 = *(const f32x2*)(cb + ((size_t)(slb_ + 1) * 256 + (S##c[1] & 255)) * 2); \
    S##g2 = *(const f32x2*)(cb + ((size_t)(slb_ + 2) * 256 + (S##c[2] & 255)) * 2); \
    S##g3 = *(const f32x2*)(cb + ((size_t)(slb_ + 3) * 256 + (S##c[3] & 255)) * 2); }

#define G2_PACK(S, BUF) { \
    *(ushort8*)&Ab[BUF][aOffA] = S##a0; \
    *(ushort8*)&Ab[BUF][aOffB] = S##a1; \
    uint32x4 bw_; \
    bw_[0] = cvtpk(S##g0[0], S##g0[1]); bw_[1] = cvtpk(S##g1[0], S##g1[1]); \
    bw_[2] = cvtpk(S##g2[0], S##g2[1]); bw_[3] = cvtpk(S##g3[0], S##g3[1]); \
    *(uint32x4*)&Bb[BUF][bOff] = bw_; }

#define G2_COMPUTE(BUF) { \
    short8 af_[4], bf_[4]; \
    _Pragma("unroll") for (int mf_ = 0; mf_ < 4; ++mf_) af_[mf_] = *(const short8*)&Ab[BUF][aBase + mf_ * 512]; \
    _Pragma("unroll") for (int nf_ = 0; nf_ < 4; ++nf_) bf_[nf_] = *(const short8*)&Bb[BUF][bBase + nf_ * 512]; \
    __builtin_amdgcn_s_setprio(1); \
    _Pragma("unroll") for (int mf_ = 0; mf_ < 4; ++mf_) \
      _Pragma("unroll") for (int nf_ = 0; nf_ < 4; ++nf_) \
        acc[mf_][nf_] = __builtin_amdgcn_mfma_f32_16x16x32_bf16(af_[mf_], bf_[nf_], acc[mf_][nf_], 0, 0, 0); \
    __builtin_amdgcn_s_setprio(0); }

  G2_IC(P, 0)
  G2_IC(Q, 1)
  G2_IG(P, 0)
  G2_PACK(P, 0)
  BARRIER()

  #pragma unroll 1
  for (int u = 0; u < 16; u += 2) {
    G2_IC(P, u + 2)
    G2_IG(Q, u + 1)
    G2_COMPUTE(0)
    G2_PACK(Q, 1)
    BARRIER()
    G2_IC(Q, u + 3)
    G2_IG(P, u + 2)
    G2_COMPUTE(1)
    if (u + 2 < 16) { G2_PACK(P, 0) }
    BARRIER()
  }

  // ---- epilogue: + b2, then column-wise log_softmax over the 256 rows ----
  float b2v[4];
  #pragma unroll
  for (int nf = 0; nf < 4; ++nf) {
    int col = n0 + wcol * 64 + nf * 16 + fr;
    b2v[nf] = (col < OUT_) ? b2[col] : 0.f;
  }
  #pragma unroll
  for (int mf = 0; mf < 4; ++mf)
    #pragma unroll
    for (int nf = 0; nf < 4; ++nf)
      #pragma unroll
      for (int j = 0; j < 4; ++j) acc[mf][nf][j] += b2v[nf];

  float cmax[4];
  #pragma unroll
  for (int nf = 0; nf < 4; ++nf) {
    float m = -3.4e38f;
    #pragma unroll
    for (int mf = 0; mf < 4; ++mf)
      #pragma unroll
      for (int j = 0; j < 4; ++j) m = fmaxf(m, acc[mf][nf][j]);
    m = fmaxf(m, __shfl_xor(m, 16, 64));
    m = fmaxf(m, __shfl_xor(m, 32, 64));
    cmax[nf] = m;
  }
  if (lane < 16) {
    #pragma unroll
    for (int nf = 0; nf < 4; ++nf) sred[wrow][wcol * 64 + nf * 16 + lane] = cmax[nf];
  }
  __syncthreads();
  float cm[4];
  #pragma unroll
  for (int nf = 0; nf < 4; ++nf) {
    int ci = wcol * 64 + nf * 16 + fr;
    cm[nf] = fmaxf(fmaxf(sred[0][ci], sred[1][ci]), fmaxf(sred[2][ci], sred[3][ci]));
  }
  __syncthreads();

  float cs[4];
  #pragma unroll
  for (int nf = 0; nf < 4; ++nf) {
    float sum = 0.f;
    #pragma unroll
    for (int mf = 0; mf < 4; ++mf)
      #pragma unroll
      for (int j = 0; j < 4; ++j) sum += expf(acc[mf][nf][j] - cm[nf]);
    sum += __shfl_xor(sum, 16, 64);
    sum += __shfl_xor(sum, 32, 64);
    cs[nf] = sum;
  }
  if (lane < 16) {
    #pragma unroll
    for (int nf = 0; nf < 4; ++nf) sred[wrow][wcol * 64 + nf * 16 + lane] = cs[nf];
  }
  __syncthreads();
  float lden[4];
  #pragma unroll
  for (int nf = 0; nf < 4; ++nf) {
    int ci = wcol * 64 + nf * 16 + fr;
    lden[nf] = logf(sred[0][ci] + sred[1][ci] + sred[2][ci] + sred[3][ci]);
  }

  #pragma unroll
  for (int mf = 0; mf < 4; ++mf) {
    #pragma unroll
    for (int nf = 0; nf < 4; ++nf) {
      int col = n0 + wcol * 64 + nf * 16 + fr;
      if (col < OUT_) {
        int row0 = wrow * 64 + mf * 16 + fq * 4;
        #pragma unroll
        for (int j = 0; j < 4; ++j)
          out[(size_t)(row0 + j) * OUT_ + col] = acc[mf][nf][j] - cm[nf] - lden[nf];
      }
    }
  }
}

// ---------------------------------------------------------------------------
extern "C" void kernel_launch(void* const* d_in, const int* in_sizes, int n_in,
                              void* d_out, int out_size, void* d_ws, size_t ws_size,
                              hipStream_t stream) {
  const float* x      = (const float*)d_in[0];
  const float* w1     = (const float*)d_in[1];
  const float* b1     = (const float*)d_in[2];
  const float* cb     = (const float*)d_in[3];
  const int*   codes  = (const int*)d_in[4];
  const float* b2     = (const float*)d_in[5];
  float* out = (float*)d_out;

  char* ws = (char*)d_ws;
  unsigned short* part = (unsigned short*)ws;                          // 33.6 MB
  unsigned short* hbf  = (unsigned short*)(ws + (size_t)KSPLIT * B_ * H_ * 2);

  hipLaunchKernelGGL(k_gemm1,    dim3(2 * KSPLIT),          dim3(512), 0, stream, x, w1, part);
  hipLaunchKernelGGL(k_reduce_h, dim3((B_ * H_ / 4) / 256), dim3(256), 0, stream, part, b1, hbf);
  hipLaunchKernelGGL(k_gemm2,    dim3(OUTP_ / 128),         dim3(512), 0, stream, hbf, codes, cb, b2, out);
}

// Round 14
// 101.480 us; speedup vs baseline: 1.2520x; 1.0255x over previous
//
#include <hip/hip_runtime.h>
#include <cstdint>
#include <cstddef>

#define B_ 256
#define IN_ 100000
#define H_ 512
#define OUT_ 30000
#define OUTP_ 30080
#define S_ 256
#define NSTEPS 3125   // IN_/32
#define KSPLIT 128

typedef __attribute__((ext_vector_type(4))) float f32x4;
typedef __attribute__((ext_vector_type(2))) float f32x2;
typedef __attribute__((ext_vector_type(4))) int i32x4;
typedef __attribute__((ext_vector_type(8))) short short8;
typedef __attribute__((ext_vector_type(8))) unsigned short ushort8;
typedef __attribute__((ext_vector_type(4))) unsigned short ushort4_;
typedef __attribute__((ext_vector_type(2))) uint32_t uint32x2;
typedef __attribute__((ext_vector_type(4))) uint32_t uint32x4;

static __device__ __forceinline__ uint32_t cvtpk(float lo, float hi) {
  uint32_t r;
  asm("v_cvt_pk_bf16_f32 %0, %1, %2" : "=v"(r) : "v"(lo), "v"(hi));
  return r;
}
static __device__ __forceinline__ unsigned short f2bf(float f) {
  union { float f; uint32_t u; } c; c.f = f;
  uint32_t u = c.u;
  u += 0x7FFFu + ((u >> 16) & 1u);   // RNE
  return (unsigned short)(u >> 16);
}
static __device__ __forceinline__ float bf2f(unsigned short h) {
  union { uint32_t u; float f; } c; c.u = ((uint32_t)h) << 16;
  return c.f;
}
// 16B fp32 -> 8B bf16 store
static __device__ __forceinline__ void pack4_store(unsigned short* dst, f32x4 a) {
  uint32x2 v;
  v[0] = cvtpk(a[0], a[1]); v[1] = cvtpk(a[2], a[3]);
  *(uint32x2*)dst = v;
}

// Raw barrier: only drain LDS ops; in-flight global loads survive.
#define BARRIER() { asm volatile("s_waitcnt lgkmcnt(0)" ::: "memory"); \
    __builtin_amdgcn_s_barrier(); \
    __builtin_amdgcn_sched_barrier(0); }

// ---------------------------------------------------------------------------
// GEMM1 split-K — SESSION-BEST configuration (r11, 101.8us), restored after
// the r12/r13 A/Bs:
//   - 256x256 tile, KSPLIT=128, grid 256 (1 block/CU), 8 waves of 64x128.
//   - w1 staged via __builtin_nontemporal_load — THE session's big win
//     (r10: 120.4 -> 102.3us). Mechanism (confirmed): zero-line-reuse w1
//     fills were burning the ~1 x 128B-line/cy/XCD L2 fill budget.
//   - Everything else CACHED. r12: nt on part/out STORES = -25% (nt defeats
//     L2 write-combining; 8B/4B-per-lane stores become partial-line DRAM
//     RMWs). r13: nt on part/codes LOADS = -2.3% (those streams have
//     cache-LINE-level multi-thread reuse; w1 does not — "zero reuse" must
//     be judged at line granularity).
// ---------------------------------------------------------------------------
__global__ __launch_bounds__(512, 2) void k_gemm1(const float* __restrict__ x,
                                                  const float* __restrict__ w1,
                                                  unsigned short* __restrict__ part) {
  __shared__ alignas(16) unsigned short Ab[2][B_ * 32];    // 16 KB each
  __shared__ alignas(16) unsigned short Bb[2][256 * 32];   // 16 KB each
  const int tid = threadIdx.x;
  // 256 blocks: xcd = d&7, i = d>>3 (0..31); kc = xcd + 8*(i>>1); nblk = i&1.
  const int d = blockIdx.x;
  const int xcd = d & 7;
  const int i = d >> 3;
  const int kc = xcd + ((i >> 1) << 3);   // 0..127
  const int nblk = i & 1;                  // 0..1
  const int s0 = (kc * NSTEPS) / KSPLIT;
  const int s1 = ((kc + 1) * NSTEPS) / KSPLIT;
  const int U = s1 - s0;   // 24 or 25 for all kc

  // A staging: 8 threads/row, lane-contiguous 16B; rows arow+{0,64,128,192}
  const int arow = tid >> 3;                    // 0..63
  const int asl = tid & 7;                      // 16B slot in 128B row-step
  const size_t rowStride64 = (size_t)64 * IN_;
  const float* gA = x + (size_t)arow * IN_ + (size_t)s0 * 32 + asl * 4;
  const int afz = (arow >> 1) & 3;              // swizzle (row+64j invariant)
  const int aslSw = ((asl >> 1) ^ afz) * 8 + (asl & 1) * 4;  // ushort offset in row

  // B staging: 8 threads/row, lane-contiguous 16B; rows br+{0,64,128,192} of 256
  const int br = tid >> 3;                      // 0..63
  const int bj = tid & 7;
  const float* gB = w1 + (size_t)(nblk * 256 + br) * IN_ + (size_t)s0 * 32 + bj * 4;
  const int bOff = br * 32 + (((bj >> 1) ^ ((br >> 1) & 3)) * 8) + (bj & 1) * 4;

  const int lane = tid & 63;
  const int wid = tid >> 6;
  const int wrow = wid >> 1;                    // 0..3  (64-row stripe)
  const int wcol = wid & 1;                     // 0..1  (128-col stripe)
  const int fr = lane & 15;
  const int fq = lane >> 4;                     // 0..3 (16B k-slot)
  const int Ra = wrow * 64 + fr;
  const int Rb = wcol * 128 + fr;
  const int aBase = Ra * 32 + (fq ^ ((Ra >> 1) & 3)) * 8;
  const int bBase = Rb * 32 + (fq ^ ((Rb >> 1) & 3)) * 8;

  f32x4 zero = {0.f, 0.f, 0.f, 0.f};
  f32x4 acc[4][8];
  #pragma unroll
  for (int mf = 0; mf < 4; ++mf)
    #pragma unroll
    for (int nf = 0; nf < 8; ++nf) acc[mf][nf] = zero;

  f32x4 P0, P1, P2, P3, P4, P5, P6, P7;
  f32x4 Q0, Q1, Q2, Q3, Q4, Q5, Q6, Q7;

#define G1_ISSUE(S, u) if ((u) < U) { \
    const float* pa_ = gA + (size_t)(u) * 32; \
    S##0 = *(const f32x4*)pa_; \
    S##1 = *(const f32x4*)(pa_ + rowStride64); \
    S##2 = *(const f32x4*)(pa_ + 2 * rowStride64); \
    S##3 = *(const f32x4*)(pa_ + 3 * rowStride64); \
    const float* pb_ = gB + (size_t)(u) * 32; \
    S##4 = __builtin_nontemporal_load((const f32x4*)pb_); \
    S##5 = __builtin_nontemporal_load((const f32x4*)(pb_ + rowStride64)); \
    S##6 = __builtin_nontemporal_load((const f32x4*)(pb_ + 2 * rowStride64)); \
    S##7 = __builtin_nontemporal_load((const f32x4*)(pb_ + 3 * rowStride64)); }

#define G1_PACK(S, b) { \
    pack4_store(&Ab[b][(arow)       * 32 + aslSw], S##0); \
    pack4_store(&Ab[b][(arow + 64)  * 32 + aslSw], S##1); \
    pack4_store(&Ab[b][(arow + 128) * 32 + aslSw], S##2); \
    pack4_store(&Ab[b][(arow + 192) * 32 + aslSw], S##3); \
    pack4_store(&Bb[b][bOff], S##4); \
    pack4_store(&Bb[b][bOff +  64 * 32], S##5); \
    pack4_store(&Bb[b][bOff + 128 * 32], S##6); \
    pack4_store(&Bb[b][bOff + 192 * 32], S##7); }

#define COMPUTE_TILE(b) { \
    short8 af_[4], bf_[8]; \
    _Pragma("unroll") for (int mf_ = 0; mf_ < 4; ++mf_) af_[mf_] = *(const short8*)&Ab[b][aBase + mf_ * 512]; \
    _Pragma("unroll") for (int nf_ = 0; nf_ < 8; ++nf_) bf_[nf_] = *(const short8*)&Bb[b][bBase + nf_ * 512]; \
    __builtin_amdgcn_s_setprio(1); \
    _Pragma("unroll") for (int mf_ = 0; mf_ < 4; ++mf_) \
      _Pragma("unroll") for (int nf_ = 0; nf_ < 8; ++nf_) \
        acc[mf_][nf_] = __builtin_amdgcn_mfma_f32_16x16x32_bf16(af_[mf_], bf_[nf_], acc[mf_][nf_], 0, 0, 0); \
    __builtin_amdgcn_s_setprio(0); }

  // prologue: 2 steps in flight, step 0 staged
  G1_ISSUE(P, 0)
  G1_ISSUE(Q, 1)
  G1_PACK(P, 0)
  BARRIER()

  int u = 0;
  #pragma unroll 1
  while (u + 1 < U) {
    G1_ISSUE(P, u + 2)
    COMPUTE_TILE(0)               // step u
    G1_PACK(Q, 1)                 // step u+1
    BARRIER()
    G1_ISSUE(Q, u + 3)
    COMPUTE_TILE(1)               // step u+1
    if (u + 2 < U) { G1_PACK(P, 0) }
    BARRIER()
    u += 2;
  }
  if (u < U) COMPUTE_TILE(0)      // U odd (25): last step

  unsigned short* pp = part + (size_t)kc * (B_ * H_);
  #pragma unroll
  for (int mf = 0; mf < 4; ++mf) {
    #pragma unroll
    for (int nf = 0; nf < 8; ++nf) {
      const int row0 = wrow * 64 + mf * 16 + fq * 4;
      const int col = nblk * 256 + wcol * 128 + nf * 16 + fr;
      #pragma unroll
      for (int j = 0; j < 4; ++j)
        pp[(size_t)(row0 + j) * H_ + col] = f2bf(acc[mf][nf][j]);
    }
  }
}

// ---------------------------------------------------------------------------
// h_bf16[m][n] = bf16(relu(b1[n] + sum_kc partial))
// Cached loads (r13 A/B: nt here = -2.3%; part lines have 8-load reuse).
// ---------------------------------------------------------------------------
__global__ void k_reduce_h(const unsigned short* __restrict__ part,
                           const float* __restrict__ b1,
                           unsigned short* __restrict__ hbf) {
  int t = blockIdx.x * 256 + threadIdx.x;        // 0..32767
  int base = t * 4;
  int n = base & (H_ - 1);
  float a0 = b1[n], a1 = b1[n + 1], a2 = b1[n + 2], a3 = b1[n + 3];
  #pragma unroll 8
  for (int kc = 0; kc < KSPLIT; ++kc) {
    ushort4_ v = *(const ushort4_*)(part + (size_t)kc * (B_ * H_) + base);
    a0 += bf2f(v[0]); a1 += bf2f(v[1]); a2 += bf2f(v[2]); a3 += bf2f(v[3]);
  }
  ushort4_ o;
  o[0] = f2bf(fmaxf(a0, 0.f));
  o[1] = f2bf(fmaxf(a1, 0.f));
  o[2] = f2bf(fmaxf(a2, 0.f));
  o[3] = f2bf(fmaxf(a3, 0.f));
  *(ushort4_*)(hbf + base) = o;
}

// ---------------------------------------------------------------------------
// GEMM2 (256 x 128-col tile x K=512), direct codebook gather, fused column
// log_softmax. All cached (r12/r13 A/Bs: nt on codes loads or out stores
// regresses).
// ---------------------------------------------------------------------------
__global__ __launch_bounds__(512, 2) void k_gemm2(const unsigned short* __restrict__ hbf,
                                                  const int* __restrict__ codes,
                                                  const float* __restrict__ cb,
                                                  const float* __restrict__ b2,
                                                  float* __restrict__ out) {
  __shared__ alignas(16) unsigned short Ab[2][B_ * 32];
  __shared__ alignas(16) unsigned short Bb[2][128 * 32];
  __shared__ float sred[4][128];
  const int tid = threadIdx.x;
  const int n0 = blockIdx.x * 128;

  // A staging: 4 threads/row, lane-contiguous 16B; rows arow2+{0,128}
  const int arow2 = tid >> 2;                   // 0..127
  const int asl2 = tid & 3;                     // 16B slot in 64B row-step
  const unsigned short* gA = hbf + (size_t)arow2 * H_ + asl2 * 8;
  const int afz2 = (arow2 >> 1) & 3;            // (row+128) invariant
  const int aslSw2 = (asl2 ^ afz2) * 8;
  const int aOffA = arow2 * 32 + aslSw2;
  const int aOffB = (arow2 + 128) * 32 + aslSw2;

  // B staging: thread -> row rb (4 threads/row), slot-quad s4 (4 codebook slots)
  const int rb = tid >> 2;
  const int s4 = tid & 3;
  const int rbo = (n0 + rb < OUT_) ? (n0 + rb) : (OUT_ - 1);
  const int* gC = codes + (size_t)rbo * S_ + s4 * 4;
  const int bOff = rb * 32 + (s4 ^ ((rb >> 1) & 3)) * 8;

  const int lane = tid & 63;
  const int wid = tid >> 6;
  const int wrow = wid >> 1;
  const int wcol = wid & 1;
  const int fr = lane & 15;
  const int fq = lane >> 4;
  const int Ra = wrow * 64 + fr;
  const int Rb = wcol * 64 + fr;
  const int aBase = Ra * 32 + (fq ^ ((Ra >> 1) & 3)) * 8;
  const int bBase = Rb * 32 + (fq ^ ((Rb >> 1) & 3)) * 8;

  f32x4 zero = {0.f, 0.f, 0.f, 0.f};
  f32x4 acc[4][4];
  #pragma unroll
  for (int mf = 0; mf < 4; ++mf)
    #pragma unroll
    for (int nf = 0; nf < 4; ++nf) acc[mf][nf] = zero;

  ushort8 Pa0, Pa1, Qa0, Qa1;
  i32x4 Pc, Qc;
  f32x2 Pg0, Pg1, Pg2, Pg3, Qg0, Qg1, Qg2, Qg3;

#define G2_IC(S, u) if ((u) < 16) { \
    S##a0 = *(const ushort8*)(gA + (size_t)(u) * 32); \
    S##a1 = *(const ushort8*)(gA + (size_t)(u) * 32 + (size_t)128 * H_); \
    S##c  = *(const i32x4*)(gC + (u) * 16); }

#define G2_IG(S, u) if ((u) < 16) { \
    const int slb_ = (u) * 16 + s4 * 4; \
    S##g0 = *(const f32x2*)(cb + ((size_t)(slb_ + 0) * 256 + (S##c[0] & 255)) * 2); \
    S##g1 = *(const f32x2*)(cb + ((size_t)(slb_ + 1) * 256 + (S##c[1] & 255)) * 2); \
    S##g2 = *(const f32x2*)(cb + ((size_t)(slb_ + 2) * 256 + (S##c[2] & 255)) * 2); \
    S##g3 = *(const f32x2*)(cb + ((size_t)(slb_ + 3) * 256 + (S##c[3] & 255)) * 2); }

#define G2_PACK(S, BUF) { \
    *(ushort8*)&Ab[BUF][aOffA] = S##a0; \
    *(ushort8*)&Ab[BUF][aOffB] = S##a1; \
    uint32x4 bw_; \
    bw_[0] = cvtpk(S##g0[0], S##g0[1]); bw_[1] = cvtpk(S##g1[0], S##g1[1]); \
    bw_[2] = cvtpk(S##g2[0], S##g2[1]); bw_[3] = cvtpk(S##g3[0], S##g3[1]); \
    *(uint32x4*)&Bb[BUF][bOff] = bw_; }

#define G2_COMPUTE(BUF) { \
    short8 af_[4], bf_[4]; \
    _Pragma("unroll") for (int mf_ = 0; mf_ < 4; ++mf_) af_[mf_] = *(const short8*)&Ab[BUF][aBase + mf_ * 512]; \
    _Pragma("unroll") for (int nf_ = 0; nf_ < 4; ++nf_) bf_[nf_] = *(const short8*)&Bb[BUF][bBase + nf_ * 512]; \
    __builtin_amdgcn_s_setprio(1); \
    _Pragma("unroll") for (int mf_ = 0; mf_ < 4; ++mf_) \
      _Pragma("unroll") for (int nf_ = 0; nf_ < 4; ++nf_) \
        acc[mf_][nf_] = __builtin_amdgcn_mfma_f32_16x16x32_bf16(af_[mf_], bf_[nf_], acc[mf_][nf_], 0, 0, 0); \
    __builtin_amdgcn_s_setprio(0); }

  G2_IC(P, 0)
  G2_IC(Q, 1)
  G2_IG(P, 0)
  G2_PACK(P, 0)
  BARRIER()

  #pragma unroll 1
  for (int u = 0; u < 16; u += 2) {
    G2_IC(P, u + 2)
    G2_IG(Q, u + 1)
    G2_COMPUTE(0)
    G2_PACK(Q, 1)
    BARRIER()
    G2_IC(Q, u + 3)
    G2_IG(P, u + 2)
    G2_COMPUTE(1)
    if (u + 2 < 16) { G2_PACK(P, 0) }
    BARRIER()
  }

  // ---- epilogue: + b2, then column-wise log_softmax over the 256 rows ----
  float b2v[4];
  #pragma unroll
  for (int nf = 0; nf < 4; ++nf) {
    int col = n0 + wcol * 64 + nf * 16 + fr;
    b2v[nf] = (col < OUT_) ? b2[col] : 0.f;
  }
  #pragma unroll
  for (int mf = 0; mf < 4; ++mf)
    #pragma unroll
    for (int nf = 0; nf < 4; ++nf)
      #pragma unroll
      for (int j = 0; j < 4; ++j) acc[mf][nf][j] += b2v[nf];

  float cmax[4];
  #pragma unroll
  for (int nf = 0; nf < 4; ++nf) {
    float m = -3.4e38f;
    #pragma unroll
    for (int mf = 0; mf < 4; ++mf)
      #pragma unroll
      for (int j = 0; j < 4; ++j) m = fmaxf(m, acc[mf][nf][j]);
    m = fmaxf(m, __shfl_xor(m, 16, 64));
    m = fmaxf(m, __shfl_xor(m, 32, 64));
    cmax[nf] = m;
  }
  if (lane < 16) {
    #pragma unroll
    for (int nf = 0; nf < 4; ++nf) sred[wrow][wcol * 64 + nf * 16 + lane] = cmax[nf];
  }
  __syncthreads();
  float cm[4];
  #pragma unroll
  for (int nf = 0; nf < 4; ++nf) {
    int ci = wcol * 64 + nf * 16 + fr;
    cm[nf] = fmaxf(fmaxf(sred[0][ci], sred[1][ci]), fmaxf(sred[2][ci], sred[3][ci]));
  }
  __syncthreads();

  float cs[4];
  #pragma unroll
  for (int nf = 0; nf < 4; ++nf) {
    float sum = 0.f;
    #pragma unroll
    for (int mf = 0; mf < 4; ++mf)
      #pragma unroll
      for (int j = 0; j < 4; ++j) sum += expf(acc[mf][nf][j] - cm[nf]);
    sum += __shfl_xor(sum, 16, 64);
    sum += __shfl_xor(sum, 32, 64);
    cs[nf] = sum;
  }
  if (lane < 16) {
    #pragma unroll
    for (int nf = 0; nf < 4; ++nf) sred[wrow][wcol * 64 + nf * 16 + lane] = cs[nf];
  }
  __syncthreads();
  float lden[4];
  #pragma unroll
  for (int nf = 0; nf < 4; ++nf) {
    int ci = wcol * 64 + nf * 16 + fr;
    lden[nf] = logf(sred[0][ci] + sred[1][ci] + sred[2][ci] + sred[3][ci]);
  }

  #pragma unroll
  for (int mf = 0; mf < 4; ++mf) {
    #pragma unroll
    for (int nf = 0; nf < 4; ++nf) {
      int col = n0 + wcol * 64 + nf * 16 + fr;
      if (col < OUT_) {
        int row0 = wrow * 64 + mf * 16 + fq * 4;
        #pragma unroll
        for (int j = 0; j < 4; ++j)
          out[(size_t)(row0 + j) * OUT_ + col] = acc[mf][nf][j] - cm[nf] - lden[nf];
      }
    }
  }
}

// ---------------------------------------------------------------------------
extern "C" void kernel_launch(void* const* d_in, const int* in_sizes, int n_in,
                              void* d_out, int out_size, void* d_ws, size_t ws_size,
                              hipStream_t stream) {
  const float* x      = (const float*)d_in[0];
  const float* w1     = (const float*)d_in[1];
  const float* b1     = (const float*)d_in[2];
  const float* cb     = (const float*)d_in[3];
  const int*   codes  = (const int*)d_in[4];
  const float* b2     = (const float*)d_in[5];
  float* out = (float*)d_out;

  char* ws = (char*)d_ws;
  unsigned short* part = (unsigned short*)ws;                          // 33.6 MB
  unsigned short* hbf  = (unsigned short*)(ws + (size_t)KSPLIT * B_ * H_ * 2);

  hipLaunchKernelGGL(k_gemm1,    dim3(2 * KSPLIT),          dim3(512), 0, stream, x, w1, part);
  hipLaunchKernelGGL(k_reduce_h, dim3((B_ * H_ / 4) / 256), dim3(256), 0, stream, part, b1, hbf);
  hipLaunchKernelGGL(k_gemm2,    dim3(OUTP_ / 128),         dim3(512), 0, stream, hbf, codes, cb, b2, out);
}